// Round 19
// baseline (409.551 us; speedup 1.0000x reference)
//
#include <hip/hip_runtime.h>
#include <hip/hip_bf16.h>

#define B_ 16
#define C_ 256
#define H_ 64
#define W_ 64
#define HW_ 4096

typedef __attribute__((ext_vector_type(4))) float f32x4;
typedef __attribute__((ext_vector_type(16))) float f32x16;
typedef __attribute__((ext_vector_type(8))) short short8;

__device__ short g_zero[2048];   // zero-initialized .bss page, never written

__device__ __forceinline__ short bf16_of(float f) {
    union { float f; unsigned u; } v; v.f = f;
    unsigned r = v.u + 0x7fffu + ((v.u >> 16) & 1u);  // round-to-nearest-even
    return (short)(r >> 16);
}

__device__ __forceinline__ void gload16(const void* g, void* l) {
    __builtin_amdgcn_global_load_lds(
        (const __attribute__((address_space(1))) void*)g,
        (__attribute__((address_space(3))) void*)l, 16, 0, 0);
}

// ---------------------------------------------------------------------------
// Weight re-layout into 32x32x16 MFMA B-fragment order:
//   Wf[tap][otile32(8)][k16(16)][lane(64)][8]  (bf16)
//   lane l holds och = otile*32 + (l&31), k = k16*16 + (l>>5)*8 + j
// ---------------------------------------------------------------------------
__global__ void prep_w_k(const float* __restrict__ w3, const float* __restrict__ w5,
                         short* __restrict__ W3f, short* __restrict__ W5f) {
    int idx = blockIdx.x * 256 + threadIdx.x;
    const int n5 = 25 * 65536;
    if (idx < n5) {
        int j = idx & 7, lane = (idx >> 3) & 63, k16 = (idx >> 9) & 15,
            otile = (idx >> 13) & 7, tap = idx >> 16;
        int o = otile * 32 + (lane & 31);
        int c = k16 * 16 + ((lane >> 5) << 3) + j;
        int ky = tap / 5, kx = tap % 5;
        W5f[idx] = bf16_of(w5[((o * C_ + c) * 5 + ky) * 5 + kx]);
    } else {
        int i2 = idx - n5;
        if (i2 < 9 * 65536) {
            int j = i2 & 7, lane = (i2 >> 3) & 63, k16 = (i2 >> 9) & 15,
                otile = (i2 >> 13) & 7, tap = i2 >> 16;
            int o = otile * 32 + (lane & 31);
            int c = k16 * 16 + ((lane >> 5) << 3) + j;
            int ky = tap / 3, kx = tap % 3;
            W3f[i2] = bf16_of(w3[((o * C_ + c) * 3 + ky) * 3 + kx]);
        }
    }
}

// ---------------------------------------------------------------------------
// x: NCHW fp32 -> Xt: [b][pixel][c] bf16 (NHWC), LDS-tiled 64ch x 64px.
// ---------------------------------------------------------------------------
__global__ void transpose_k(const float* __restrict__ x, short* __restrict__ Xt) {
    __shared__ float tile[64][65];
    int bid = blockIdx.x;
    int cblk = bid & 3, pblk = (bid >> 2) & 63, b = bid >> 8;
    int t = threadIdx.x;
    const float* xb = x + (size_t)(b * C_ + cblk * 64) * HW_ + pblk * 64;
    int px = t & 63, c4 = t >> 6;
    #pragma unroll
    for (int it = 0; it < 16; ++it) {
        int ci = c4 + it * 4;
        tile[ci][px] = xb[(size_t)ci * HW_ + px];
    }
    __syncthreads();
    short* xtb = Xt + (size_t)(b * HW_ + pblk * 64) * C_ + cblk * 64;
    int c8 = (t & 7) * 8, pw0 = t >> 3;
    #pragma unroll
    for (int it = 0; it < 2; ++it) {
        int pw = pw0 + it * 32;
        short8 v;
        #pragma unroll
        for (int k = 0; k < 8; ++k) v[k] = bf16_of(tile[c8 + k][pw]);
        *(short8*)(xtb + (size_t)pw * C_ + c8) = v;
    }
}

// ---------------------------------------------------------------------------
// Global average pool (fp64, deterministic tree).
// ---------------------------------------------------------------------------
__global__ void gpool_k(const float* __restrict__ x, double* __restrict__ gp) {
    __shared__ double red[256];
    int bc = blockIdx.x;
    const float* p = x + (size_t)bc * HW_;
    double s = 0.0;
    for (int i = threadIdx.x; i < HW_; i += 256) s += (double)p[i];
    red[threadIdx.x] = s;
    __syncthreads();
    for (int st = 128; st > 0; st >>= 1) {
        if (threadIdx.x < st) red[threadIdx.x] += red[threadIdx.x + st];
        __syncthreads();
    }
    if (threadIdx.x == 0) gp[bc] = red[0];
}

__global__ void gvec_k(const double* __restrict__ gp, const float* __restrict__ grw,
                       const float* __restrict__ grb, double* __restrict__ g) {
    int b = blockIdx.x;
    int o = threadIdx.x >> 6, lane = threadIdx.x & 63;
    double s = 0.0;
    for (int c = lane; c < C_; c += 64)
        s += gp[b * C_ + c] * (double)grw[o * C_ + c];
    #pragma unroll
    for (int off = 32; off > 0; off >>= 1) s += __shfl_down(s, off);
    if (lane == 0) g[b * 4 + o] = s * (1.0 / 4096.0) + (double)grb[o];
}

// ---------------------------------------------------------------------------
// Per-pixel routing (fp64): softmax -> top2 -> renorm.
// ---------------------------------------------------------------------------
__global__ void routing_k(const float* __restrict__ x, const float* __restrict__ srw,
                          const float* __restrict__ srb, const double* __restrict__ g,
                          float* __restrict__ w4) {
    __shared__ double red[4][64][4];
    int t = threadIdx.x;
    int pl = t & 63, part = t >> 6;
    int p = blockIdx.x * 64 + pl;
    int b = p >> 12, pix = p & 4095;
    const float* xb = x + (size_t)b * C_ * HW_ + pix;
    double s[4] = {0, 0, 0, 0};
    for (int c = part * 64; c < part * 64 + 64; ++c) {
        double xv = (double)xb[(size_t)c * HW_];
        #pragma unroll
        for (int o = 0; o < 4; ++o) s[o] += xv * (double)srw[o * C_ + c];
    }
    #pragma unroll
    for (int o = 0; o < 4; ++o) red[part][pl][o] = s[o];
    __syncthreads();
    if (part == 0) {
        double l[4];
        #pragma unroll
        for (int o = 0; o < 4; ++o)
            l[o] = red[0][pl][o] + red[1][pl][o] + red[2][pl][o] + red[3][pl][o]
                   + (double)srb[o] + g[b * 4 + o];
        double m = fmax(fmax(l[0], l[1]), fmax(l[2], l[3]));
        double e[4], sum = 0.0;
        #pragma unroll
        for (int o = 0; o < 4; ++o) { e[o] = exp(l[o] - m); sum += e[o]; }
        double wv[4];
        #pragma unroll
        for (int o = 0; o < 4; ++o) wv[o] = e[o] / sum;
        int i1 = 0;
        for (int o = 1; o < 4; ++o) if (wv[o] > wv[i1]) i1 = o;
        int i2 = (i1 == 0) ? 1 : 0;
        for (int o = 0; o < 4; ++o) { if (o == i1) continue; if (wv[o] > wv[i2]) i2 = o; }
        double sc = 1.0 / (wv[i1] + wv[i2] + 1e-6);
        #pragma unroll
        for (int o = 0; o < 4; ++o) {
            float r = (o == i1 || o == i2) ? (float)(wv[o] * sc) : 0.0f;
            w4[((size_t)b * 4 + o) * HW_ + pix] = r;
        }
    }
}

// ---------------------------------------------------------------------------
// Fused conv3 + conv5 + avgpool + identity + mixing. R18 pipeline semantics
// (rolled tap loop, single-buffered A, depth-1 B prefetch, scalarized B
// addressing, 3 waves/SIMD) re-shaped onto mfma_f32_32x32x16_bf16: wave =
// 2 M-tiles (32px) x 1 N-tile (32och), 4 K16 substeps/tap. MFMA-pipe cycles
// drop 17% (8.07cy/32K FLOP vs 4.85/16K) and MFMA inst count drops 4x,
// freeing issue slots. acc = 2x16 f32 x 2 convs = 64 AGPR (unchanged).
// ---------------------------------------------------------------------------
__launch_bounds__(256, 3)
__global__ void conv_fused_k(const short* __restrict__ Xt, const short* __restrict__ W5f,
                             const short* __restrict__ W3f, const float* __restrict__ x,
                             const float* __restrict__ w4, const float* __restrict__ b3,
                             const float* __restrict__ b5, float* __restrict__ out) {
    __shared__ __align__(16) char lds[5 * 68 * 128];   // 43520 B; epilogue reuses
    // locality swizzle: XCD k (bid&7) sequentially runs swz = k*256 + (bid>>3)
    int swz = ((blockIdx.x & 7) << 8) | (blockIdx.x >> 3);
    int h = swz & 63, nb = (swz >> 6) & 1, b = swz >> 7;
    int t = threadIdx.x;
    int wv = t >> 6, lane = t & 63;
    int l31 = lane & 31, l5 = lane >> 5;

    f32x16 acc5[2], acc3[2];
    #pragma unroll
    for (int mi = 0; mi < 2; ++mi) {
        #pragma unroll
        for (int e = 0; e < 16; ++e) { acc5[mi][e] = 0.f; acc3[mi][e] = 0.f; }
    }

    // zero the 4 always-out-of-image halo cols (0,1,66,67) x 5 rows, once
    if (t < 160) {
        int part = t & 7, ci = (t >> 3) & 3, row = t >> 5;
        int col = (ci < 2) ? ci : (64 + ci);   // 0,1,66,67
        *(short8*)(lds + (row * 68 + col) * 128 + part * 16) = (short8){0,0,0,0,0,0,0,0};
    }

    const size_t xt_b = (size_t)b * HW_ * C_;
    const short* zp = g_zero;

    // wave-uniform otile base (scalar via readfirstlane)
    const int wvu = __builtin_amdgcn_readfirstlane(wv);
    const int otile32 = nb * 4 + wvu;          // 32-och tile index
    const short* W5l = W5f + (size_t)lane * 8;
    const short* W3l = W3f + (size_t)lane * 8;

    for (int chunk = 0; chunk < 4; ++chunk) {
        int c0 = chunk * 64;
        __syncthreads();   // prior chunk's reads done (and halo-zero visible)
        // stage A slab: interior cols 2..65 (gc 0..63): 5 rows x 8 grp x 8 parts
        #pragma unroll
        for (int it = 0; it < 10; ++it) {
            int idx = t + it * 256;
            int part = idx & 7;            // dest 16B slot within pixel
            int ci   = (idx >> 3) & 7;     // col within group (lane>>3)
            int g8   = (idx >> 6) & 7;     // col group      (wave-uniform)
            int row  = idx >> 9;           // 0..4           (wave-uniform)
            int col  = 2 + g8 * 8 + ci;
            int gr = h + row - 2, gc = g8 * 8 + ci;
            int p = part ^ (col & 7);      // inverse-swizzled source part
            const short* src = ((unsigned)gr < 64u)
                ? Xt + xt_b + (size_t)(gr * 64 + gc) * 256 + c0 + p * 8
                : zp + ((idx & 63) << 3);
            gload16(src, lds + (row * 68 + 2 + g8 * 8) * 128);
        }
        __syncthreads();   // drains vmcnt -> slab ready

        const int k16b = chunk * 4;
        short8 av[2], b5f[2], b3f[2];

        // ---- prologue: B for (tap0, s0).  tap0 outer -> b5 only ----
        b5f[0] = *(const short8*)(W5l +
            (size_t)((0 * 8 + otile32) * 16 + k16b) * 512);

        int dy = -2, dx = -2;
        for (int tap = 0; tap < 25; ++tap) {
            const bool inner = (dy >= -1 && dy <= 1 && dx >= -1 && dx <= 1);
            const int tap3 = (dy + 1) * 3 + (dx + 1);
            const int ndx = (dx == 2) ? -2 : dx + 1;
            const int ndy = (dx == 2) ? dy + 1 : dy;
            const bool innern = (ndy >= -1 && ndy <= 1 && ndx >= -1 && ndx <= 1);
            const int tap3n = (ndy + 1) * 3 + (ndx + 1);

            #pragma unroll
            for (int s = 0; s < 4; ++s) {
                const int cur = s & 1, nxt = cur ^ 1;
                // A for this substep (ds_read, used this substep)
                #pragma unroll
                for (int mi = 0; mi < 2; ++mi) {
                    int col_s = mi * 32 + l31 + dx + 2;
                    int kb = s * 32 + l5 * 16;
                    av[mi] = *(const short8*)(lds + ((dy + 2) * 68 + col_s) * 128
                                               + (kb ^ ((col_s & 7) << 4)));
                }
                // prefetch B for next substep (the L2-latency stream)
                if (s < 3) {
                    b5f[nxt] = *(const short8*)(W5l +
                        (size_t)((tap * 8 + otile32) * 16 + k16b + s + 1) * 512);
                    if (inner)
                        b3f[nxt] = *(const short8*)(W3l +
                            (size_t)((tap3 * 8 + otile32) * 16 + k16b + s + 1) * 512);
                } else if (tap < 24) {
                    b5f[nxt] = *(const short8*)(W5l +
                        (size_t)(((tap + 1) * 8 + otile32) * 16 + k16b) * 512);
                    if (innern)
                        b3f[nxt] = *(const short8*)(W3l +
                            (size_t)((tap3n * 8 + otile32) * 16 + k16b) * 512);
                }
                // MFMAs for this substep (B loaded 1 substep ago)
                __builtin_amdgcn_s_setprio(1);
                acc5[0] = __builtin_amdgcn_mfma_f32_32x32x16_bf16(
                    av[0], b5f[cur], acc5[0], 0, 0, 0);
                acc5[1] = __builtin_amdgcn_mfma_f32_32x32x16_bf16(
                    av[1], b5f[cur], acc5[1], 0, 0, 0);
                if (inner) {
                    acc3[0] = __builtin_amdgcn_mfma_f32_32x32x16_bf16(
                        av[0], b3f[cur], acc3[0], 0, 0, 0);
                    acc3[1] = __builtin_amdgcn_mfma_f32_32x32x16_bf16(
                        av[1], b3f[cur], acc3[1], 0, 0, 0);
                }
                __builtin_amdgcn_s_setprio(0);
            }
            dy = ndy; dx = ndx;
        }
    }

    // ---- epilogue: avgpool (fp32 from original x), identity, mixing ----
    __syncthreads();
    float* colsum = (float*)lds;             // [128][65] padded
    float* w4row = colsum + 128 * 65;        // [4][64]
    for (int idx = t; idx < 128 * 64; idx += 256) {
        int ch = idx >> 6, px = idx & 63;
        const float* xp = x + (size_t)(b * C_ + nb * 128 + ch) * HW_ + px;
        float s = xp[h * 64];
        if (h > 0) s += xp[(h - 1) * 64];
        if (h < 63) s += xp[(h + 1) * 64];
        colsum[ch * 65 + px] = s;
    }
    {
        int o = t >> 6, px = t & 63;
        w4row[o * 64 + px] = w4[((size_t)b * 4 + o) * HW_ + h * 64 + px];
    }
    __syncthreads();

    // C/D layout (32x32, guide-verified): och = lane&31,
    // px = mi*32 + (e>>2)*8 + 4*(lane>>5) + (e&3)
    {
        int ch_l = wvu * 32 + l31;
        int ch = nb * 128 + ch_l;
        float b3v = b3[ch], b5v = b5[ch];
        const size_t orow = ((size_t)(b * C_ + ch) * H_ + h) * W_;
        #pragma unroll
        for (int mi = 0; mi < 2; ++mi) {
            #pragma unroll
            for (int q = 0; q < 4; ++q) {
                int px0 = mi * 32 + q * 8 + l5 * 4;
                f32x4 res;
                #pragma unroll
                for (int rr = 0; rr < 4; ++rr) {
                    int px = px0 + rr;
                    float c3 = acc3[mi][q * 4 + rr] + b3v;
                    float c5 = acc5[mi][q * 4 + rr] + b5v;
                    float cs = colsum[ch_l * 65 + px];
                    float csl = (px > 0) ? colsum[ch_l * 65 + px - 1] : 0.f;
                    float csr = (px < 63) ? colsum[ch_l * 65 + px + 1] : 0.f;
                    float ap = (cs + csl + csr) * (1.0f / 9.0f);
                    float xv = x[orow + px];
                    float w0 = w4row[px], w1 = w4row[64 + px], w2 = w4row[128 + px],
                          w3v = w4row[192 + px];
                    res[rr] = w0 * xv + w1 * c3 + w2 * c5 + w3v * ap;
                }
                *(f32x4*)(out + orow + px0) = res;
            }
        }
    }
}

// ---------------------------------------------------------------------------
extern "C" void kernel_launch(void* const* d_in, const int* in_sizes, int n_in,
                              void* d_out, int out_size, void* d_ws, size_t ws_size,
                              hipStream_t stream) {
    const float* x   = (const float*)d_in[0];
    const float* grw = (const float*)d_in[1];
    const float* grb = (const float*)d_in[2];
    const float* srw = (const float*)d_in[3];
    const float* srb = (const float*)d_in[4];
    const float* c3w = (const float*)d_in[5];
    const float* c3b = (const float*)d_in[6];
    const float* c5w = (const float*)d_in[7];
    const float* c5b = (const float*)d_in[8];
    float* out = (float*)d_out;
    char* ws = (char*)d_ws;

    short*  Xt  = (short*)(ws);                 // 33,554,432  NHWC bf16 x
    short*  W5f = (short*)(ws + 33554432);      //  3,276,800  conv5 fragments
    short*  W3f = (short*)(ws + 36831232);      //  1,179,648  conv3 fragments
    float*  w4  = (float*)(ws + 38010880);      //  1,048,576  routing weights
    double* gp  = (double*)(ws + 39059456);     //     32,768  global pool sums
    double* g   = (double*)(ws + 39092224);     //        512  router logits

    prep_w_k   <<<8704, 256, 0, stream>>>(c3w, c5w, W3f, W5f);
    transpose_k<<<4096, 256, 0, stream>>>(x, Xt);
    gpool_k    <<<4096, 256, 0, stream>>>(x, gp);
    gvec_k     <<<16,   256, 0, stream>>>(gp, grw, grb, g);
    routing_k  <<<1024, 256, 0, stream>>>(x, srw, srb, g, w4);
    conv_fused_k<<<2048, 256, 0, stream>>>(Xt, W5f, W3f, x, w4, c3b, c5b, out);
}

// Round 20
// 346.491 us; speedup vs baseline: 1.1820x; 1.1820x over previous
//
#include <hip/hip_runtime.h>
#include <hip/hip_bf16.h>

#define B_ 16
#define C_ 256
#define H_ 64
#define W_ 64
#define HW_ 4096

typedef __attribute__((ext_vector_type(4))) float f32x4;
typedef __attribute__((ext_vector_type(8))) short short8;

__device__ short g_zero[2048];   // zero-initialized .bss page, never written

__device__ __forceinline__ short bf16_of(float f) {
    union { float f; unsigned u; } v; v.f = f;
    unsigned r = v.u + 0x7fffu + ((v.u >> 16) & 1u);  // round-to-nearest-even
    return (short)(r >> 16);
}

__device__ __forceinline__ void gload16(const void* g, void* l) {
    __builtin_amdgcn_global_load_lds(
        (const __attribute__((address_space(1))) void*)g,
        (__attribute__((address_space(3))) void*)l, 16, 0, 0);
}

// ---------------------------------------------------------------------------
// Weight re-layout into MFMA B-fragment order:
//   Wf[tap][otile(16)][kstep(8)][lane(64)][8]  (bf16)
// ---------------------------------------------------------------------------
__global__ void prep_w_k(const float* __restrict__ w3, const float* __restrict__ w5,
                         short* __restrict__ W3f, short* __restrict__ W5f) {
    int idx = blockIdx.x * 256 + threadIdx.x;
    const int n5 = 25 * 65536;
    if (idx < n5) {
        int j = idx & 7, lane = (idx >> 3) & 63, kstep = (idx >> 9) & 7,
            otile = (idx >> 12) & 15, tap = idx >> 16;
        int o = otile * 16 + (lane & 15);
        int c = kstep * 32 + ((lane >> 4) << 3) + j;
        int ky = tap / 5, kx = tap % 5;
        W5f[idx] = bf16_of(w5[((o * C_ + c) * 5 + ky) * 5 + kx]);
    } else {
        int i2 = idx - n5;
        if (i2 < 9 * 65536) {
            int j = i2 & 7, lane = (i2 >> 3) & 63, kstep = (i2 >> 9) & 7,
                otile = (i2 >> 12) & 15, tap = i2 >> 16;
            int o = otile * 16 + (lane & 15);
            int c = kstep * 32 + ((lane >> 4) << 3) + j;
            int ky = tap / 3, kx = tap % 3;
            W3f[i2] = bf16_of(w3[((o * C_ + c) * 3 + ky) * 3 + kx]);
        }
    }
}

// ---------------------------------------------------------------------------
// x: NCHW fp32 -> Xt: [b][pixel][c] bf16 (NHWC), LDS-tiled 64ch x 64px.
// ---------------------------------------------------------------------------
__global__ void transpose_k(const float* __restrict__ x, short* __restrict__ Xt) {
    __shared__ float tile[64][65];
    int bid = blockIdx.x;
    int cblk = bid & 3, pblk = (bid >> 2) & 63, b = bid >> 8;
    int t = threadIdx.x;
    const float* xb = x + (size_t)(b * C_ + cblk * 64) * HW_ + pblk * 64;
    int px = t & 63, c4 = t >> 6;
    #pragma unroll
    for (int it = 0; it < 16; ++it) {
        int ci = c4 + it * 4;
        tile[ci][px] = xb[(size_t)ci * HW_ + px];
    }
    __syncthreads();
    short* xtb = Xt + (size_t)(b * HW_ + pblk * 64) * C_ + cblk * 64;
    int c8 = (t & 7) * 8, pw0 = t >> 3;
    #pragma unroll
    for (int it = 0; it < 2; ++it) {
        int pw = pw0 + it * 32;
        short8 v;
        #pragma unroll
        for (int k = 0; k < 8; ++k) v[k] = bf16_of(tile[c8 + k][pw]);
        *(short8*)(xtb + (size_t)pw * C_ + c8) = v;
    }
}

// ---------------------------------------------------------------------------
// Global average pool (fp64, deterministic tree).
// ---------------------------------------------------------------------------
__global__ void gpool_k(const float* __restrict__ x, double* __restrict__ gp) {
    __shared__ double red[256];
    int bc = blockIdx.x;
    const float* p = x + (size_t)bc * HW_;
    double s = 0.0;
    for (int i = threadIdx.x; i < HW_; i += 256) s += (double)p[i];
    red[threadIdx.x] = s;
    __syncthreads();
    for (int st = 128; st > 0; st >>= 1) {
        if (threadIdx.x < st) red[threadIdx.x] += red[threadIdx.x + st];
        __syncthreads();
    }
    if (threadIdx.x == 0) gp[bc] = red[0];
}

__global__ void gvec_k(const double* __restrict__ gp, const float* __restrict__ grw,
                       const float* __restrict__ grb, double* __restrict__ g) {
    int b = blockIdx.x;
    int o = threadIdx.x >> 6, lane = threadIdx.x & 63;
    double s = 0.0;
    for (int c = lane; c < C_; c += 64)
        s += gp[b * C_ + c] * (double)grw[o * C_ + c];
    #pragma unroll
    for (int off = 32; off > 0; off >>= 1) s += __shfl_down(s, off);
    if (lane == 0) g[b * 4 + o] = s * (1.0 / 4096.0) + (double)grb[o];
}

// ---------------------------------------------------------------------------
// Per-pixel routing (fp64): softmax -> top2 -> renorm.
// ---------------------------------------------------------------------------
__global__ void routing_k(const float* __restrict__ x, const float* __restrict__ srw,
                          const float* __restrict__ srb, const double* __restrict__ g,
                          float* __restrict__ w4) {
    __shared__ double red[4][64][4];
    int t = threadIdx.x;
    int pl = t & 63, part = t >> 6;
    int p = blockIdx.x * 64 + pl;
    int b = p >> 12, pix = p & 4095;
    const float* xb = x + (size_t)b * C_ * HW_ + pix;
    double s[4] = {0, 0, 0, 0};
    for (int c = part * 64; c < part * 64 + 64; ++c) {
        double xv = (double)xb[(size_t)c * HW_];
        #pragma unroll
        for (int o = 0; o < 4; ++o) s[o] += xv * (double)srw[o * C_ + c];
    }
    #pragma unroll
    for (int o = 0; o < 4; ++o) red[part][pl][o] = s[o];
    __syncthreads();
    if (part == 0) {
        double l[4];
        #pragma unroll
        for (int o = 0; o < 4; ++o)
            l[o] = red[0][pl][o] + red[1][pl][o] + red[2][pl][o] + red[3][pl][o]
                   + (double)srb[o] + g[b * 4 + o];
        double m = fmax(fmax(l[0], l[1]), fmax(l[2], l[3]));
        double e[4], sum = 0.0;
        #pragma unroll
        for (int o = 0; o < 4; ++o) { e[o] = exp(l[o] - m); sum += e[o]; }
        double wv[4];
        #pragma unroll
        for (int o = 0; o < 4; ++o) wv[o] = e[o] / sum;
        int i1 = 0;
        for (int o = 1; o < 4; ++o) if (wv[o] > wv[i1]) i1 = o;
        int i2 = (i1 == 0) ? 1 : 0;
        for (int o = 0; o < 4; ++o) { if (o == i1) continue; if (wv[o] > wv[i2]) i2 = o; }
        double sc = 1.0 / (wv[i1] + wv[i2] + 1e-6);
        #pragma unroll
        for (int o = 0; o < 4; ++o) {
            float r = (o == i1 || o == i2) ? (float)(wv[o] * sc) : 0.0f;
            w4[((size_t)b * 4 + o) * HW_ + pix] = r;
        }
    }
}

// ---------------------------------------------------------------------------
// Fused conv3 + conv5 + avgpool + identity + mixing. R18 (best verified):
// rolled tap loop, single-buffered A (LDS, same-half), depth-1 prefetch of
// both B streams (L2), SGPR-scalarized B addressing via readfirstlane +
// lane-hoisted W5l/W3l, 3 waves/SIMD, XCD locality swizzle, source-swizzled
// global_load_lds A-staging, setprio around MFMA clusters.
// 32x32 MFMA re-shape (R19) is a PROVEN dead end: banks span one 128B pixel
// row, so a 32-lane M-tile read at wave-uniform kb is structurally 4-way
// conflicted (26M conflicts, -25%). 16x16 splits lanes into 4 kb-slots -> 2-way (free).
// ---------------------------------------------------------------------------
__launch_bounds__(256, 3)
__global__ void conv_fused_k(const short* __restrict__ Xt, const short* __restrict__ W5f,
                             const short* __restrict__ W3f, const float* __restrict__ x,
                             const float* __restrict__ w4, const float* __restrict__ b3,
                             const float* __restrict__ b5, float* __restrict__ out) {
    __shared__ __align__(16) char lds[5 * 68 * 128];   // 43520 B; epilogue reuses
    // locality swizzle: XCD k (bid&7) sequentially runs swz = k*256 + (bid>>3)
    int swz = ((blockIdx.x & 7) << 8) | (blockIdx.x >> 3);
    int h = swz & 63, nb = (swz >> 6) & 1, b = swz >> 7;
    int t = threadIdx.x;
    int wv = t >> 6, lane = t & 63;
    int l15 = lane & 15, l4 = lane >> 4;

    f32x4 acc5[4][2], acc3[4][2];
    #pragma unroll
    for (int mi = 0; mi < 4; ++mi)
        #pragma unroll
        for (int ni = 0; ni < 2; ++ni) {
            acc5[mi][ni] = (f32x4){0.f, 0.f, 0.f, 0.f};
            acc3[mi][ni] = (f32x4){0.f, 0.f, 0.f, 0.f};
        }

    // zero the 4 always-out-of-image halo cols (0,1,66,67) x 5 rows, once
    if (t < 160) {
        int part = t & 7, ci = (t >> 3) & 3, row = t >> 5;
        int col = (ci < 2) ? ci : (64 + ci);   // 0,1,66,67
        *(short8*)(lds + (row * 68 + col) * 128 + part * 16) = (short8){0,0,0,0,0,0,0,0};
    }

    const size_t xt_b = (size_t)b * HW_ * C_;
    const short* zp = g_zero;

    // wave-uniform otile base, proven scalar via readfirstlane (HK tech. 5)
    const int wvu = __builtin_amdgcn_readfirstlane(wv);
    const int otile0 = nb * 8 + wvu * 2;
    // lane-dependent address part hoisted once; all per-step offsets scalar
    const short* W5l = W5f + (size_t)lane * 8;
    const short* W3l = W3f + (size_t)lane * 8;

    for (int chunk = 0; chunk < 4; ++chunk) {
        int c0 = chunk * 64;
        __syncthreads();   // prior chunk's reads done (and halo-zero visible)
        // stage A slab: interior cols 2..65 (gc 0..63): 5 rows x 8 grp x 8 parts
        #pragma unroll
        for (int it = 0; it < 10; ++it) {
            int idx = t + it * 256;
            int part = idx & 7;            // dest 16B slot within pixel
            int ci   = (idx >> 3) & 7;     // col within group (lane>>3)
            int g8   = (idx >> 6) & 7;     // col group      (wave-uniform)
            int row  = idx >> 9;           // 0..4           (wave-uniform)
            int col  = 2 + g8 * 8 + ci;
            int gr = h + row - 2, gc = g8 * 8 + ci;
            int p = part ^ (col & 7);      // inverse-swizzled source part
            const short* src = ((unsigned)gr < 64u)
                ? Xt + xt_b + (size_t)(gr * 64 + gc) * 256 + c0 + p * 8
                : zp + ((idx & 63) << 3);
            gload16(src, lds + (row * 68 + 2 + g8 * 8) * 128);
        }
        __syncthreads();   // drains vmcnt -> slab ready

        const int kst0 = chunk * 2, kst1 = chunk * 2 + 1;
        short8 av[4], b5X[2], b5Y[2], b3X[2], b3Y[2];

        // ---- prologue: B for (tap0, kk0).  tap0 = (dy=-2,dx=-2), outer ----
        #pragma unroll
        for (int ni = 0; ni < 2; ++ni)
            b5X[ni] = *(const short8*)(W5l +
                (size_t)(((otile0 + ni) * 8 + kst0)) * 512);

        int dy = -2, dx = -2;
        for (int tap = 0; tap < 25; ++tap) {
            const bool inner = (dy >= -1 && dy <= 1 && dx >= -1 && dx <= 1);
            const int tap3 = (dy + 1) * 3 + (dx + 1);
            const int ndx = (dx == 2) ? -2 : dx + 1;
            const int ndy = (dx == 2) ? dy + 1 : dy;

            // --- half 1: A for (tap,kk0) loaded NOW (ds_read, used this half);
            //     prefetch B(tap,kk1); compute (tap,kk0) ---
            #pragma unroll
            for (int mi = 0; mi < 4; ++mi) {
                int col_s = mi * 16 + l15 + dx + 2;
                int kb = l4 * 16;
                av[mi] = *(const short8*)(lds + ((dy + 2) * 68 + col_s) * 128
                                           + (kb ^ ((col_s & 7) << 4)));
            }
            #pragma unroll
            for (int ni = 0; ni < 2; ++ni)
                b5Y[ni] = *(const short8*)(W5l +
                    (size_t)((tap * 16 + otile0 + ni) * 8 + kst1) * 512);
            if (inner) {
                #pragma unroll
                for (int ni = 0; ni < 2; ++ni)
                    b3Y[ni] = *(const short8*)(W3l +
                        (size_t)((tap3 * 16 + otile0 + ni) * 8 + kst1) * 512);
            }
            __builtin_amdgcn_s_setprio(1);
            #pragma unroll
            for (int ni = 0; ni < 2; ++ni)
                #pragma unroll
                for (int mi = 0; mi < 4; ++mi)
                    acc5[mi][ni] = __builtin_amdgcn_mfma_f32_16x16x32_bf16(
                        av[mi], b5X[ni], acc5[mi][ni], 0, 0, 0);
            if (inner) {
                #pragma unroll
                for (int ni = 0; ni < 2; ++ni)
                    #pragma unroll
                    for (int mi = 0; mi < 4; ++mi)
                        acc3[mi][ni] = __builtin_amdgcn_mfma_f32_16x16x32_bf16(
                            av[mi], b3X[ni], acc3[mi][ni], 0, 0, 0);
            }
            __builtin_amdgcn_s_setprio(0);

            // --- half 2: A for (tap,kk1) loaded NOW; prefetch B(tap+1,kk0);
            //     compute (tap,kk1) ---
            #pragma unroll
            for (int mi = 0; mi < 4; ++mi) {
                int col_s = mi * 16 + l15 + dx + 2;
                int kb = l4 * 16 + 64;
                av[mi] = *(const short8*)(lds + ((dy + 2) * 68 + col_s) * 128
                                           + (kb ^ ((col_s & 7) << 4)));
            }
            if (tap < 24) {
                const bool innern = (ndy >= -1 && ndy <= 1 && ndx >= -1 && ndx <= 1);
                const int tap3n = (ndy + 1) * 3 + (ndx + 1);
                #pragma unroll
                for (int ni = 0; ni < 2; ++ni)
                    b5X[ni] = *(const short8*)(W5l +
                        (size_t)(((tap + 1) * 16 + otile0 + ni) * 8 + kst0) * 512);
                if (innern) {
                    #pragma unroll
                    for (int ni = 0; ni < 2; ++ni)
                        b3X[ni] = *(const short8*)(W3l +
                            (size_t)((tap3n * 16 + otile0 + ni) * 8 + kst0) * 512);
                }
            }
            __builtin_amdgcn_s_setprio(1);
            #pragma unroll
            for (int ni = 0; ni < 2; ++ni)
                #pragma unroll
                for (int mi = 0; mi < 4; ++mi)
                    acc5[mi][ni] = __builtin_amdgcn_mfma_f32_16x16x32_bf16(
                        av[mi], b5Y[ni], acc5[mi][ni], 0, 0, 0);
            if (inner) {
                #pragma unroll
                for (int ni = 0; ni < 2; ++ni)
                    #pragma unroll
                    for (int mi = 0; mi < 4; ++mi)
                        acc3[mi][ni] = __builtin_amdgcn_mfma_f32_16x16x32_bf16(
                            av[mi], b3Y[ni], acc3[mi][ni], 0, 0, 0);
            }
            __builtin_amdgcn_s_setprio(0);

            dy = ndy; dx = ndx;
        }
    }

    // ---- epilogue: avgpool (fp32 from original x), identity, mixing ----
    __syncthreads();
    float* colsum = (float*)lds;             // [128][65] padded
    float* w4row = colsum + 128 * 65;        // [4][64]
    for (int idx = t; idx < 128 * 64; idx += 256) {
        int ch = idx >> 6, px = idx & 63;
        const float* xp = x + (size_t)(b * C_ + nb * 128 + ch) * HW_ + px;
        float s = xp[h * 64];
        if (h > 0) s += xp[(h - 1) * 64];
        if (h < 63) s += xp[(h + 1) * 64];
        colsum[ch * 65 + px] = s;
    }
    {
        int o = t >> 6, px = t & 63;
        w4row[o * 64 + px] = w4[((size_t)b * 4 + o) * HW_ + h * 64 + px];
    }
    __syncthreads();

    #pragma unroll
    for (int ni = 0; ni < 2; ++ni) {
        int ch_l = wvu * 32 + ni * 16 + l15;
        int ch = nb * 128 + ch_l;
        float b3v = b3[ch], b5v = b5[ch];
        const size_t orow = ((size_t)(b * C_ + ch) * H_ + h) * W_;
        #pragma unroll
        for (int mi = 0; mi < 4; ++mi) {
            int px0 = mi * 16 + l4 * 4;
            f32x4 res;
            #pragma unroll
            for (int rr = 0; rr < 4; ++rr) {
                int px = px0 + rr;
                float c3 = acc3[mi][ni][rr] + b3v;
                float c5 = acc5[mi][ni][rr] + b5v;
                float cs = colsum[ch_l * 65 + px];
                float csl = (px > 0) ? colsum[ch_l * 65 + px - 1] : 0.f;
                float csr = (px < 63) ? colsum[ch_l * 65 + px + 1] : 0.f;
                float ap = (cs + csl + csr) * (1.0f / 9.0f);
                float xv = x[orow + px];
                float w0 = w4row[px], w1 = w4row[64 + px], w2 = w4row[128 + px],
                      w3v = w4row[192 + px];
                res[rr] = w0 * xv + w1 * c3 + w2 * c5 + w3v * ap;
            }
            *(f32x4*)(out + orow + px0) = res;
        }
    }
}

// ---------------------------------------------------------------------------
extern "C" void kernel_launch(void* const* d_in, const int* in_sizes, int n_in,
                              void* d_out, int out_size, void* d_ws, size_t ws_size,
                              hipStream_t stream) {
    const float* x   = (const float*)d_in[0];
    const float* grw = (const float*)d_in[1];
    const float* grb = (const float*)d_in[2];
    const float* srw = (const float*)d_in[3];
    const float* srb = (const float*)d_in[4];
    const float* c3w = (const float*)d_in[5];
    const float* c3b = (const float*)d_in[6];
    const float* c5w = (const float*)d_in[7];
    const float* c5b = (const float*)d_in[8];
    float* out = (float*)d_out;
    char* ws = (char*)d_ws;

    short*  Xt  = (short*)(ws);                 // 33,554,432  NHWC bf16 x
    short*  W5f = (short*)(ws + 33554432);      //  3,276,800  conv5 fragments
    short*  W3f = (short*)(ws + 36831232);      //  1,179,648  conv3 fragments
    float*  w4  = (float*)(ws + 38010880);      //  1,048,576  routing weights
    double* gp  = (double*)(ws + 39059456);     //     32,768  global pool sums
    double* g   = (double*)(ws + 39092224);     //        512  router logits

    prep_w_k   <<<8704, 256, 0, stream>>>(c3w, c5w, W3f, W5f);
    transpose_k<<<4096, 256, 0, stream>>>(x, Xt);
    gpool_k    <<<4096, 256, 0, stream>>>(x, gp);
    gvec_k     <<<16,   256, 0, stream>>>(gp, grw, grb, g);
    routing_k  <<<1024, 256, 0, stream>>>(x, srw, srb, g, w4);
    conv_fused_k<<<2048, 256, 0, stream>>>(Xt, W5f, W3f, x, w4, c3b, c5b, out);
}

// Round 21
// 318.307 us; speedup vs baseline: 1.2867x; 1.0885x over previous
//
#include <hip/hip_runtime.h>
#include <hip/hip_bf16.h>

#define B_ 16
#define C_ 256
#define H_ 64
#define W_ 64
#define HW_ 4096

typedef __attribute__((ext_vector_type(4))) float f32x4;
typedef __attribute__((ext_vector_type(8))) short short8;

__device__ short g_zero[2048];   // zero-initialized .bss page, never written

__device__ __forceinline__ short bf16_of(float f) {
    union { float f; unsigned u; } v; v.f = f;
    unsigned r = v.u + 0x7fffu + ((v.u >> 16) & 1u);  // round-to-nearest-even
    return (short)(r >> 16);
}

__device__ __forceinline__ void gload16(const void* g, void* l) {
    __builtin_amdgcn_global_load_lds(
        (const __attribute__((address_space(1))) void*)g,
        (__attribute__((address_space(3))) void*)l, 16, 0, 0);
}

// ---------------------------------------------------------------------------
// Weight re-layout into MFMA B-fragment order:
//   Wf[tap][otile(16)][kstep(8)][lane(64)][8]  (bf16)
// ---------------------------------------------------------------------------
__global__ void prep_w_k(const float* __restrict__ w3, const float* __restrict__ w5,
                         short* __restrict__ W3f, short* __restrict__ W5f) {
    int idx = blockIdx.x * 256 + threadIdx.x;
    const int n5 = 25 * 65536;
    if (idx < n5) {
        int j = idx & 7, lane = (idx >> 3) & 63, kstep = (idx >> 9) & 7,
            otile = (idx >> 12) & 15, tap = idx >> 16;
        int o = otile * 16 + (lane & 15);
        int c = kstep * 32 + ((lane >> 4) << 3) + j;
        int ky = tap / 5, kx = tap % 5;
        W5f[idx] = bf16_of(w5[((o * C_ + c) * 5 + ky) * 5 + kx]);
    } else {
        int i2 = idx - n5;
        if (i2 < 9 * 65536) {
            int j = i2 & 7, lane = (i2 >> 3) & 63, kstep = (i2 >> 9) & 7,
                otile = (i2 >> 12) & 15, tap = i2 >> 16;
            int o = otile * 16 + (lane & 15);
            int c = kstep * 32 + ((lane >> 4) << 3) + j;
            int ky = tap / 3, kx = tap % 3;
            W3f[i2] = bf16_of(w3[((o * C_ + c) * 3 + ky) * 3 + kx]);
        }
    }
}

// ---------------------------------------------------------------------------
// Transpose (x NCHW fp32 -> Xt NHWC bf16) -- plain variant (fallback path).
// ---------------------------------------------------------------------------
__global__ void transpose_k(const float* __restrict__ x, short* __restrict__ Xt) {
    __shared__ float tile[64][65];
    int bid = blockIdx.x;
    int cblk = bid & 3, pblk = (bid >> 2) & 63, b = bid >> 8;
    int t = threadIdx.x;
    const float* xb = x + (size_t)(b * C_ + cblk * 64) * HW_ + pblk * 64;
    int px = t & 63, c4 = t >> 6;
    #pragma unroll
    for (int it = 0; it < 16; ++it) {
        int ci = c4 + it * 4;
        tile[ci][px] = xb[(size_t)ci * HW_ + px];
    }
    __syncthreads();
    short* xtb = Xt + (size_t)(b * HW_ + pblk * 64) * C_ + cblk * 64;
    int c8 = (t & 7) * 8, pw0 = t >> 3;
    #pragma unroll
    for (int it = 0; it < 2; ++it) {
        int pw = pw0 + it * 32;
        short8 v;
        #pragma unroll
        for (int k = 0; k < 8; ++k) v[k] = bf16_of(tile[c8 + k][pw]);
        *(short8*)(xtb + (size_t)pw * C_ + c8) = v;
    }
}

// ---------------------------------------------------------------------------
// FUSED transpose: also emits (a) per-channel fp64 partial sums over its
// 64-pixel tile (gpool's work) and (b) per-(o,px) fp64 partial spatial
// logits over its 64-channel quarter -- ascending-ch order, identical
// summation grouping to the fallback routing_k (bit-identical fp64 logits).
// ---------------------------------------------------------------------------
__global__ void transpose_fused_k(const float* __restrict__ x,
                                  const float* __restrict__ srw,
                                  short* __restrict__ Xt,
                                  double* __restrict__ gp_part,
                                  double* __restrict__ s_part) {
    __shared__ float tile[64][65];
    __shared__ double psum[4][64];
    int bid = blockIdx.x;
    int cblk = bid & 3, pblk = (bid >> 2) & 63, b = bid >> 8;
    int t = threadIdx.x;
    const float* xb = x + (size_t)(b * C_ + cblk * 64) * HW_ + pblk * 64;
    int px = t & 63, c4 = t >> 6;
    #pragma unroll
    for (int it = 0; it < 16; ++it) {
        int ci = c4 + it * 4;
        tile[ci][px] = xb[(size_t)ci * HW_ + px];
    }
    __syncthreads();
    // Xt write (unchanged)
    short* xtb = Xt + (size_t)(b * HW_ + pblk * 64) * C_ + cblk * 64;
    int c8 = (t & 7) * 8, pw0 = t >> 3;
    #pragma unroll
    for (int it = 0; it < 2; ++it) {
        int pw = pw0 + it * 32;
        short8 v;
        #pragma unroll
        for (int k = 0; k < 8; ++k) v[k] = bf16_of(tile[c8 + k][pw]);
        *(short8*)(xtb + (size_t)pw * C_ + c8) = v;
    }
    // gpool partial: thread (ch = t&63, qt = t>>6) sums 16 px
    {
        int ch = t & 63, qt = t >> 6;
        double s = 0.0;
        #pragma unroll
        for (int k = 0; k < 16; ++k) s += (double)tile[ch][qt * 16 + k];
        psum[qt][ch] = s;
    }
    // spatial-logit partial: thread (o = t>>6, px = t&63) sums 64 ch ascending
    {
        int o = t >> 6;
        double sp = 0.0;
        for (int ch = 0; ch < 64; ++ch)
            sp += (double)tile[ch][px] * (double)srw[o * C_ + cblk * 64 + ch];
        s_part[(size_t)bid * 256 + o * 64 + px] = sp;
    }
    __syncthreads();
    if (t < 64)
        gp_part[(size_t)bid * 64 + t] =
            ((psum[0][t] + psum[1][t]) + psum[2][t]) + psum[3][t];
}

// ---------------------------------------------------------------------------
// Global average pool (fp64, deterministic tree) -- fallback path.
// ---------------------------------------------------------------------------
__global__ void gpool_k(const float* __restrict__ x, double* __restrict__ gp) {
    __shared__ double red[256];
    int bc = blockIdx.x;
    const float* p = x + (size_t)bc * HW_;
    double s = 0.0;
    for (int i = threadIdx.x; i < HW_; i += 256) s += (double)p[i];
    red[threadIdx.x] = s;
    __syncthreads();
    for (int st = 128; st > 0; st >>= 1) {
        if (threadIdx.x < st) red[threadIdx.x] += red[threadIdx.x + st];
        __syncthreads();
    }
    if (threadIdx.x == 0) gp[bc] = red[0];
}

__global__ void gvec_k(const double* __restrict__ gp, const float* __restrict__ grw,
                       const float* __restrict__ grb, double* __restrict__ g) {
    int b = blockIdx.x;
    int o = threadIdx.x >> 6, lane = threadIdx.x & 63;
    double s = 0.0;
    for (int c = lane; c < C_; c += 64)
        s += gp[b * C_ + c] * (double)grw[o * C_ + c];
    #pragma unroll
    for (int off = 32; off > 0; off >>= 1) s += __shfl_down(s, off);
    if (lane == 0) g[b * 4 + o] = s * (1.0 / 4096.0) + (double)grb[o];
}

// Fused-path gvec: reduce gp_part over pblk (fixed order), then old dot.
__global__ void gvec2_k(const double* __restrict__ gp_part,
                        const float* __restrict__ grw,
                        const float* __restrict__ grb, double* __restrict__ g) {
    __shared__ double red[256];
    int b = blockIdx.x, t = threadIdx.x;
    int cblk = t >> 6, ch = t & 63;
    double s = 0.0;
    for (int pblk = 0; pblk < 64; ++pblk)
        s += gp_part[((size_t)(b * 256 + pblk * 4 + cblk) << 6) + ch];
    red[t] = s;                      // red[c], c = cblk*64+ch = t
    __syncthreads();
    int o = t >> 6, lane = t & 63;
    double s2 = 0.0;
    for (int c = lane; c < C_; c += 64) s2 += red[c] * (double)grw[o * C_ + c];
    #pragma unroll
    for (int off = 32; off > 0; off >>= 1) s2 += __shfl_down(s2, off);
    if (lane == 0) g[b * 4 + o] = s2 * (1.0 / 4096.0) + (double)grb[o];
}

// ---------------------------------------------------------------------------
// Per-pixel routing (fp64): softmax -> top2 -> renorm -- fallback path.
// ---------------------------------------------------------------------------
__global__ void routing_k(const float* __restrict__ x, const float* __restrict__ srw,
                          const float* __restrict__ srb, const double* __restrict__ g,
                          float* __restrict__ w4) {
    __shared__ double red[4][64][4];
    int t = threadIdx.x;
    int pl = t & 63, part = t >> 6;
    int p = blockIdx.x * 64 + pl;
    int b = p >> 12, pix = p & 4095;
    const float* xb = x + (size_t)b * C_ * HW_ + pix;
    double s[4] = {0, 0, 0, 0};
    for (int c = part * 64; c < part * 64 + 64; ++c) {
        double xv = (double)xb[(size_t)c * HW_];
        #pragma unroll
        for (int o = 0; o < 4; ++o) s[o] += xv * (double)srw[o * C_ + c];
    }
    #pragma unroll
    for (int o = 0; o < 4; ++o) red[part][pl][o] = s[o];
    __syncthreads();
    if (part == 0) {
        double l[4];
        #pragma unroll
        for (int o = 0; o < 4; ++o)
            l[o] = red[0][pl][o] + red[1][pl][o] + red[2][pl][o] + red[3][pl][o]
                   + (double)srb[o] + g[b * 4 + o];
        double m = fmax(fmax(l[0], l[1]), fmax(l[2], l[3]));
        double e[4], sum = 0.0;
        #pragma unroll
        for (int o = 0; o < 4; ++o) { e[o] = exp(l[o] - m); sum += e[o]; }
        double wv[4];
        #pragma unroll
        for (int o = 0; o < 4; ++o) wv[o] = e[o] / sum;
        int i1 = 0;
        for (int o = 1; o < 4; ++o) if (wv[o] > wv[i1]) i1 = o;
        int i2 = (i1 == 0) ? 1 : 0;
        for (int o = 0; o < 4; ++o) { if (o == i1) continue; if (wv[o] > wv[i2]) i2 = o; }
        double sc = 1.0 / (wv[i1] + wv[i2] + 1e-6);
        #pragma unroll
        for (int o = 0; o < 4; ++o) {
            float r = (o == i1 || o == i2) ? (float)(wv[o] * sc) : 0.0f;
            w4[((size_t)b * 4 + o) * HW_ + pix] = r;
        }
    }
}

// Fused-path routing: logits from s_part (cblk ascending = identical
// grouping/order to fallback red[0..3]); softmax/top2/renorm verbatim.
__global__ void routing_sm_k(const double* __restrict__ s_part,
                             const float* __restrict__ srb,
                             const double* __restrict__ g,
                             float* __restrict__ w4) {
    int p = blockIdx.x * 256 + threadIdx.x;
    int b = p >> 12, pix = p & 4095;
    int pblk = pix >> 6, px = pix & 63;
    double l[4];
    #pragma unroll
    for (int o = 0; o < 4; ++o) {
        const size_t base = (size_t)(b * 256 + pblk * 4) * 256 + o * 64 + px;
        l[o] = ((s_part[base] + s_part[base + 256]) + s_part[base + 512])
               + s_part[base + 768];
        l[o] = l[o] + (double)srb[o] + g[b * 4 + o];
    }
    double m = fmax(fmax(l[0], l[1]), fmax(l[2], l[3]));
    double e[4], sum = 0.0;
    #pragma unroll
    for (int o = 0; o < 4; ++o) { e[o] = exp(l[o] - m); sum += e[o]; }
    double wv[4];
    #pragma unroll
    for (int o = 0; o < 4; ++o) wv[o] = e[o] / sum;
    int i1 = 0;
    for (int o = 1; o < 4; ++o) if (wv[o] > wv[i1]) i1 = o;
    int i2 = (i1 == 0) ? 1 : 0;
    for (int o = 0; o < 4; ++o) { if (o == i1) continue; if (wv[o] > wv[i2]) i2 = o; }
    double sc = 1.0 / (wv[i1] + wv[i2] + 1e-6);
    #pragma unroll
    for (int o = 0; o < 4; ++o) {
        float r = (o == i1 || o == i2) ? (float)(wv[o] * sc) : 0.0f;
        w4[((size_t)b * 4 + o) * HW_ + pix] = r;
    }
}

// ---------------------------------------------------------------------------
// Fused conv3 + conv5 + avgpool + identity + mixing. R18/R20 (best verified,
// reproduced): rolled tap loop, single-buffered A (LDS, same-half), depth-1
// prefetch of both B streams (L2), SGPR-scalarized B addressing, 3 waves/SIMD,
// XCD locality swizzle, source-swizzled global_load_lds A-staging, setprio.
// ---------------------------------------------------------------------------
__launch_bounds__(256, 3)
__global__ void conv_fused_k(const short* __restrict__ Xt, const short* __restrict__ W5f,
                             const short* __restrict__ W3f, const float* __restrict__ x,
                             const float* __restrict__ w4, const float* __restrict__ b3,
                             const float* __restrict__ b5, float* __restrict__ out) {
    __shared__ __align__(16) char lds[5 * 68 * 128];   // 43520 B; epilogue reuses
    int swz = ((blockIdx.x & 7) << 8) | (blockIdx.x >> 3);
    int h = swz & 63, nb = (swz >> 6) & 1, b = swz >> 7;
    int t = threadIdx.x;
    int wv = t >> 6, lane = t & 63;
    int l15 = lane & 15, l4 = lane >> 4;

    f32x4 acc5[4][2], acc3[4][2];
    #pragma unroll
    for (int mi = 0; mi < 4; ++mi)
        #pragma unroll
        for (int ni = 0; ni < 2; ++ni) {
            acc5[mi][ni] = (f32x4){0.f, 0.f, 0.f, 0.f};
            acc3[mi][ni] = (f32x4){0.f, 0.f, 0.f, 0.f};
        }

    if (t < 160) {
        int part = t & 7, ci = (t >> 3) & 3, row = t >> 5;
        int col = (ci < 2) ? ci : (64 + ci);   // 0,1,66,67
        *(short8*)(lds + (row * 68 + col) * 128 + part * 16) = (short8){0,0,0,0,0,0,0,0};
    }

    const size_t xt_b = (size_t)b * HW_ * C_;
    const short* zp = g_zero;

    const int wvu = __builtin_amdgcn_readfirstlane(wv);
    const int otile0 = nb * 8 + wvu * 2;
    const short* W5l = W5f + (size_t)lane * 8;
    const short* W3l = W3f + (size_t)lane * 8;

    for (int chunk = 0; chunk < 4; ++chunk) {
        int c0 = chunk * 64;
        __syncthreads();
        #pragma unroll
        for (int it = 0; it < 10; ++it) {
            int idx = t + it * 256;
            int part = idx & 7;
            int ci   = (idx >> 3) & 7;
            int g8   = (idx >> 6) & 7;
            int row  = idx >> 9;
            int col  = 2 + g8 * 8 + ci;
            int gr = h + row - 2, gc = g8 * 8 + ci;
            int p = part ^ (col & 7);
            const short* src = ((unsigned)gr < 64u)
                ? Xt + xt_b + (size_t)(gr * 64 + gc) * 256 + c0 + p * 8
                : zp + ((idx & 63) << 3);
            gload16(src, lds + (row * 68 + 2 + g8 * 8) * 128);
        }
        __syncthreads();

        const int kst0 = chunk * 2, kst1 = chunk * 2 + 1;
        short8 av[4], b5X[2], b5Y[2], b3X[2], b3Y[2];

        #pragma unroll
        for (int ni = 0; ni < 2; ++ni)
            b5X[ni] = *(const short8*)(W5l +
                (size_t)(((otile0 + ni) * 8 + kst0)) * 512);

        int dy = -2, dx = -2;
        for (int tap = 0; tap < 25; ++tap) {
            const bool inner = (dy >= -1 && dy <= 1 && dx >= -1 && dx <= 1);
            const int tap3 = (dy + 1) * 3 + (dx + 1);
            const int ndx = (dx == 2) ? -2 : dx + 1;
            const int ndy = (dx == 2) ? dy + 1 : dy;

            #pragma unroll
            for (int mi = 0; mi < 4; ++mi) {
                int col_s = mi * 16 + l15 + dx + 2;
                int kb = l4 * 16;
                av[mi] = *(const short8*)(lds + ((dy + 2) * 68 + col_s) * 128
                                           + (kb ^ ((col_s & 7) << 4)));
            }
            #pragma unroll
            for (int ni = 0; ni < 2; ++ni)
                b5Y[ni] = *(const short8*)(W5l +
                    (size_t)((tap * 16 + otile0 + ni) * 8 + kst1) * 512);
            if (inner) {
                #pragma unroll
                for (int ni = 0; ni < 2; ++ni)
                    b3Y[ni] = *(const short8*)(W3l +
                        (size_t)((tap3 * 16 + otile0 + ni) * 8 + kst1) * 512);
            }
            __builtin_amdgcn_s_setprio(1);
            #pragma unroll
            for (int ni = 0; ni < 2; ++ni)
                #pragma unroll
                for (int mi = 0; mi < 4; ++mi)
                    acc5[mi][ni] = __builtin_amdgcn_mfma_f32_16x16x32_bf16(
                        av[mi], b5X[ni], acc5[mi][ni], 0, 0, 0);
            if (inner) {
                #pragma unroll
                for (int ni = 0; ni < 2; ++ni)
                    #pragma unroll
                    for (int mi = 0; mi < 4; ++mi)
                        acc3[mi][ni] = __builtin_amdgcn_mfma_f32_16x16x32_bf16(
                            av[mi], b3X[ni], acc3[mi][ni], 0, 0, 0);
            }
            __builtin_amdgcn_s_setprio(0);

            #pragma unroll
            for (int mi = 0; mi < 4; ++mi) {
                int col_s = mi * 16 + l15 + dx + 2;
                int kb = l4 * 16 + 64;
                av[mi] = *(const short8*)(lds + ((dy + 2) * 68 + col_s) * 128
                                           + (kb ^ ((col_s & 7) << 4)));
            }
            if (tap < 24) {
                const bool innern = (ndy >= -1 && ndy <= 1 && ndx >= -1 && ndx <= 1);
                const int tap3n = (ndy + 1) * 3 + (ndx + 1);
                #pragma unroll
                for (int ni = 0; ni < 2; ++ni)
                    b5X[ni] = *(const short8*)(W5l +
                        (size_t)(((tap + 1) * 16 + otile0 + ni) * 8 + kst0) * 512);
                if (innern) {
                    #pragma unroll
                    for (int ni = 0; ni < 2; ++ni)
                        b3X[ni] = *(const short8*)(W3l +
                            (size_t)((tap3n * 16 + otile0 + ni) * 8 + kst0) * 512);
                }
            }
            __builtin_amdgcn_s_setprio(1);
            #pragma unroll
            for (int ni = 0; ni < 2; ++ni)
                #pragma unroll
                for (int mi = 0; mi < 4; ++mi)
                    acc5[mi][ni] = __builtin_amdgcn_mfma_f32_16x16x32_bf16(
                        av[mi], b5Y[ni], acc5[mi][ni], 0, 0, 0);
            if (inner) {
                #pragma unroll
                for (int ni = 0; ni < 2; ++ni)
                    #pragma unroll
                    for (int mi = 0; mi < 4; ++mi)
                        acc3[mi][ni] = __builtin_amdgcn_mfma_f32_16x16x32_bf16(
                            av[mi], b3Y[ni], acc3[mi][ni], 0, 0, 0);
            }
            __builtin_amdgcn_s_setprio(0);

            dy = ndy; dx = ndx;
        }
    }

    // ---- epilogue: avgpool (fp32 from original x), identity, mixing ----
    __syncthreads();
    float* colsum = (float*)lds;             // [128][65] padded
    float* w4row = colsum + 128 * 65;        // [4][64]
    for (int idx = t; idx < 128 * 64; idx += 256) {
        int ch = idx >> 6, px = idx & 63;
        const float* xp = x + (size_t)(b * C_ + nb * 128 + ch) * HW_ + px;
        float s = xp[h * 64];
        if (h > 0) s += xp[(h - 1) * 64];
        if (h < 63) s += xp[(h + 1) * 64];
        colsum[ch * 65 + px] = s;
    }
    {
        int o = t >> 6, px = t & 63;
        w4row[o * 64 + px] = w4[((size_t)b * 4 + o) * HW_ + h * 64 + px];
    }
    __syncthreads();

    #pragma unroll
    for (int ni = 0; ni < 2; ++ni) {
        int ch_l = wvu * 32 + ni * 16 + l15;
        int ch = nb * 128 + ch_l;
        float b3v = b3[ch], b5v = b5[ch];
        const size_t orow = ((size_t)(b * C_ + ch) * H_ + h) * W_;
        #pragma unroll
        for (int mi = 0; mi < 4; ++mi) {
            int px0 = mi * 16 + l4 * 4;
            f32x4 res;
            #pragma unroll
            for (int rr = 0; rr < 4; ++rr) {
                int px = px0 + rr;
                float c3 = acc3[mi][ni][rr] + b3v;
                float c5 = acc5[mi][ni][rr] + b5v;
                float cs = colsum[ch_l * 65 + px];
                float csl = (px > 0) ? colsum[ch_l * 65 + px - 1] : 0.f;
                float csr = (px < 63) ? colsum[ch_l * 65 + px + 1] : 0.f;
                float ap = (cs + csl + csr) * (1.0f / 9.0f);
                float xv = x[orow + px];
                float w0 = w4row[px], w1 = w4row[64 + px], w2 = w4row[128 + px],
                      w3v = w4row[192 + px];
                res[rr] = w0 * xv + w1 * c3 + w2 * c5 + w3v * ap;
            }
            *(f32x4*)(out + orow + px0) = res;
        }
    }
}

// ---------------------------------------------------------------------------
extern "C" void kernel_launch(void* const* d_in, const int* in_sizes, int n_in,
                              void* d_out, int out_size, void* d_ws, size_t ws_size,
                              hipStream_t stream) {
    const float* x   = (const float*)d_in[0];
    const float* grw = (const float*)d_in[1];
    const float* grb = (const float*)d_in[2];
    const float* srw = (const float*)d_in[3];
    const float* srb = (const float*)d_in[4];
    const float* c3w = (const float*)d_in[5];
    const float* c3b = (const float*)d_in[6];
    const float* c5w = (const float*)d_in[7];
    const float* c5b = (const float*)d_in[8];
    float* out = (float*)d_out;
    char* ws = (char*)d_ws;

    short*  Xt  = (short*)(ws);                 // 33,554,432  NHWC bf16 x
    short*  W5f = (short*)(ws + 33554432);      //  3,276,800  conv5 fragments
    short*  W3f = (short*)(ws + 36831232);      //  1,179,648  conv3 fragments
    float*  w4  = (float*)(ws + 38010880);      //  1,048,576  routing weights
    double* g   = (double*)(ws + 39059456);     //        512  router logits
    // fused-path extras:
    double* gp_part = (double*)(ws + 39059968); //  2,097,152  gpool partials
    double* s_part  = (double*)(ws + 41157120); //  8,388,608  logit partials
    // fused total: 49,545,728 B.  Fallback reuses gp_part region for gp.
    double* gp = gp_part;                       //     32,768  (fallback only)

    const bool fused = (ws_size >= 49545728ull);

    prep_w_k<<<8704, 256, 0, stream>>>(c3w, c5w, W3f, W5f);
    if (fused) {
        transpose_fused_k<<<4096, 256, 0, stream>>>(x, srw, Xt, gp_part, s_part);
        gvec2_k   <<<16,  256, 0, stream>>>(gp_part, grw, grb, g);
        routing_sm_k<<<256, 256, 0, stream>>>(s_part, srb, g, w4);
    } else {
        transpose_k<<<4096, 256, 0, stream>>>(x, Xt);
        gpool_k    <<<4096, 256, 0, stream>>>(x, gp);
        gvec_k     <<<16,   256, 0, stream>>>(gp, grw, grb, g);
        routing_k  <<<1024, 256, 0, stream>>>(x, srw, srb, g, w4);
    }
    conv_fused_k<<<2048, 256, 0, stream>>>(Xt, W5f, W3f, x, w4, c3b, c5b, out);
}